// Round 9
// baseline (330.714 us; speedup 1.0000x reference)
//
#include <hip/hip_runtime.h>

#define DD 256
#define NGRAPH 64
#define NCLS 60
#define BN_EPS 1e-5f
#define AGG_BLOCKS 2048
#define AGG_WAVES (AGG_BLOCKS * 4)
#define POOL_PARTS 16

typedef __attribute__((ext_vector_type(8))) short bf16x8;
typedef __attribute__((ext_vector_type(4))) float f32x4;

__device__ __forceinline__ unsigned short f2bf(float f) {
    union { float f; unsigned u; } v;
    v.f = f;
    unsigned r = v.u + 0x7FFFu + ((v.u >> 16) & 1u);  // RNE
    return (unsigned short)(r >> 16);
}
__device__ __forceinline__ float bf2f(unsigned short u) {
    union { unsigned u; float f; } v;
    v.u = ((unsigned)u) << 16;
    return v.f;
}

// ---------------- degree ----------------
__global__ void k_degcount(const int* __restrict__ dst, int E, int* __restrict__ degcnt) {
    int e = blockIdx.x * blockDim.x + threadIdx.x;
    if (e < E) atomicAdd(&degcnt[dst[e]], 1);
}

// ---------------- fused: block 0 = single-block exclusive scan -> rowptr & fillcur;
//                  blocks 1..64 = W transpose+convert (4 cols each, 1024 thr) ----------------
__global__ __launch_bounds__(1024) void k_scanwt(const int* __restrict__ deg, int N, int E,
                                                 int* __restrict__ rowptr,
                                                 int* __restrict__ fillcur,
                                                 const float* __restrict__ W,
                                                 unsigned short* __restrict__ Wt) {
    if (blockIdx.x > 0) {
        int nb = blockIdx.x - 1;                    // 0..63
        int n = nb * 4 + (threadIdx.x >> 8);        // col of W^T
        int k = threadIdx.x & 255;
        Wt[n * DD + k] = f2bf(W[k * DD + n]);
        return;
    }
    __shared__ int sm[1024];
    const int t = threadIdx.x;
    const int CH = (N + 1023) >> 10;
    const int i0 = min(N, t * CH), i1 = min(N, i0 + CH);
    int s = 0;
    for (int i = i0; i < i1; ++i) s += deg[i];
    sm[t] = s;
    __syncthreads();
    for (int off = 1; off < 1024; off <<= 1) {
        int v = (t >= off) ? sm[t - off] : 0;
        __syncthreads();
        sm[t] += v;
        __syncthreads();
    }
    int base = (t > 0) ? sm[t - 1] : 0;  // exclusive prefix
    for (int i = i0; i < i1; ++i) {
        int d = deg[i];
        rowptr[i] = base;
        fillcur[i] = base;
        base += d;
    }
    if (t == 1023) rowptr[N] = sm[1023];
}

// ---------------- CSR bucket fill: packed 4B (src:16 | norm_bf16:16), cursor = fillcur ----------------
__global__ void k_fill(const int* __restrict__ src, const int* __restrict__ dst,
                       const int* __restrict__ degcnt, int* __restrict__ fillcur,
                       int E, unsigned* __restrict__ esw) {
    int e = blockIdx.x * blockDim.x + threadIdx.x;
    if (e >= E) return;
    int s = src[e], d = dst[e];
    float w = rsqrtf((float)(degcnt[s] + 1)) * rsqrtf((float)(degcnt[d] + 1));
    int slot = atomicAdd(&fillcur[d], 1);
    esw[slot] = (unsigned)s | ((unsigned)f2bf(w) << 16);  // N < 65536
}

// ---------------- MFMA GEMM: 128x256 tile (full width), 512 threads ----------------
#define GBM 128
#define GBN 256
__global__ __launch_bounds__(512) void k_gemm_mfma(const float* __restrict__ A,
                                                   const unsigned short* __restrict__ Wtg,
                                                   unsigned short* __restrict__ C, int M) {
    __shared__ short Wt[GBN * 256];  // full weight [n][k] bf16, XOR-swizzled, 128 KB
    __shared__ short At[GBM * 32];   // [row][k] bf16 per k-step, swizzled, 8 KB
    const int tid = threadIdx.x;
    const int wave = tid >> 6;
    const int lane = tid & 63;
    const int row0 = blockIdx.x * GBM;

#pragma unroll
    for (int i = 0; i < 16; ++i) {
        int cid = tid + i * 512;
        int n = cid >> 5;
        int k0 = (cid & 31) * 8;
        bf16x8 pk = *(const bf16x8*)&Wtg[(size_t)n * DD + k0];
        int byte = (n * 512 + k0 * 2) ^ ((n & 7) << 4);
        *(bf16x8*)((char*)Wt + byte) = pk;
    }

    f32x4 acc[16];
#pragma unroll
    for (int j = 0; j < 16; ++j) acc[j] = (f32x4){0.f, 0.f, 0.f, 0.f};

    const int arow = tid >> 2;
    const int aslot = tid & 3;
    const int grow = row0 + arow;
    const int frow = wave * 16 + (lane & 15);
    const int g = lane >> 4;
    const int abyte_st = (arow * 64 + aslot * 16) ^ ((arow & 3) << 4);
    const float* ap = (grow < M) ? &A[(size_t)grow * DD + aslot * 8] : nullptr;

    float4 va = make_float4(0.f, 0.f, 0.f, 0.f);
    float4 vb = make_float4(0.f, 0.f, 0.f, 0.f);
    if (ap) { va = *(const float4*)ap; vb = *(const float4*)(ap + 4); }

    for (int kb = 0; kb < DD; kb += 32) {
        __syncthreads();
        {
            bf16x8 pk;
            pk[0] = (short)f2bf(va.x); pk[1] = (short)f2bf(va.y);
            pk[2] = (short)f2bf(va.z); pk[3] = (short)f2bf(va.w);
            pk[4] = (short)f2bf(vb.x); pk[5] = (short)f2bf(vb.y);
            pk[6] = (short)f2bf(vb.z); pk[7] = (short)f2bf(vb.w);
            *(bf16x8*)((char*)At + abyte_st) = pk;
        }
        __syncthreads();

        if (kb + 32 < DD && ap) {
            va = *(const float4*)(ap + kb + 32);
            vb = *(const float4*)(ap + kb + 36);
        }

        int abyte = (frow * 64 + g * 16) ^ ((frow & 3) << 4);
        bf16x8 af = *(const bf16x8*)((const char*)At + abyte);
#pragma unroll
        for (int j = 0; j < 16; ++j) {
            int n = j * 16 + (lane & 15);
            int bbyte = (n * 512 + (kb + g * 8) * 2) ^ ((n & 7) << 4);
            bf16x8 bfr = *(const bf16x8*)((const char*)Wt + bbyte);
            acc[j] = __builtin_amdgcn_mfma_f32_16x16x32_bf16(af, bfr, acc[j], 0, 0, 0);
        }
    }

#pragma unroll
    for (int j = 0; j < 16; ++j) {
        int col = j * 16 + (lane & 15);
#pragma unroll
        for (int r = 0; r < 4; ++r) {
            int row = row0 + wave * 16 + g * 4 + r;
            if (row < M) C[(size_t)row * DD + col] = f2bf(acc[j][r]);
        }
    }
}

// ---------------- pull aggregation (persistent, full row/wave) + BN partials (block-reduced) ----------------
__global__ __launch_bounds__(256) void k_aggpull(const unsigned short* __restrict__ xwb,
                                                 const int* __restrict__ rowptr,
                                                 const unsigned* __restrict__ esw,
                                                 const int* __restrict__ degcnt,
                                                 const float* __restrict__ b,
                                                 unsigned short* __restrict__ aggb,
                                                 float* __restrict__ ps,
                                                 float* __restrict__ ps2, int N) {
    __shared__ float sred[4 * DD];
    __shared__ float qred[4 * DD];
    const int lane = threadIdx.x & 63;
    const int wave = threadIdx.x >> 6;
    const int c = lane * 4;
    const int gw = (blockIdx.x * blockDim.x + threadIdx.x) >> 6;
    const float4 bb = *(const float4*)&b[c];

    float s0 = 0.f, s1 = 0.f, s2 = 0.f, s3 = 0.f;
    float q0 = 0.f, q1 = 0.f, q2 = 0.f, q3 = 0.f;

    for (int n = gw; n < N; n += AGG_WAVES) {
        float di = rsqrtf((float)(degcnt[n] + 1));
        float w0 = di * di;
        ushort4 v = *(const ushort4*)&xwb[(size_t)n * DD + c];
        float4 acc = make_float4(bf2f(v.x) * w0, bf2f(v.y) * w0, bf2f(v.z) * w0, bf2f(v.w) * w0);

        int j0 = rowptr[n], j1 = rowptr[n + 1];
        int j = j0;
        for (; j + 3 < j1; j += 4) {
            unsigned e0 = esw[j + 0], e1 = esw[j + 1], e2 = esw[j + 2], e3 = esw[j + 3];
            ushort4 u0 = *(const ushort4*)&xwb[(size_t)(e0 & 0xFFFFu) * DD + c];
            ushort4 u1 = *(const ushort4*)&xwb[(size_t)(e1 & 0xFFFFu) * DD + c];
            ushort4 u2 = *(const ushort4*)&xwb[(size_t)(e2 & 0xFFFFu) * DD + c];
            ushort4 u3 = *(const ushort4*)&xwb[(size_t)(e3 & 0xFFFFu) * DD + c];
            float wa = bf2f((unsigned short)(e0 >> 16));
            float wb = bf2f((unsigned short)(e1 >> 16));
            float wc = bf2f((unsigned short)(e2 >> 16));
            float wd = bf2f((unsigned short)(e3 >> 16));
            acc.x += bf2f(u0.x) * wa + bf2f(u1.x) * wb + bf2f(u2.x) * wc + bf2f(u3.x) * wd;
            acc.y += bf2f(u0.y) * wa + bf2f(u1.y) * wb + bf2f(u2.y) * wc + bf2f(u3.y) * wd;
            acc.z += bf2f(u0.z) * wa + bf2f(u1.z) * wb + bf2f(u2.z) * wc + bf2f(u3.z) * wd;
            acc.w += bf2f(u0.w) * wa + bf2f(u1.w) * wb + bf2f(u2.w) * wc + bf2f(u3.w) * wd;
        }
        for (; j < j1; ++j) {
            unsigned e0 = esw[j];
            float wa = bf2f((unsigned short)(e0 >> 16));
            ushort4 u0 = *(const ushort4*)&xwb[(size_t)(e0 & 0xFFFFu) * DD + c];
            acc.x += bf2f(u0.x) * wa;
            acc.y += bf2f(u0.y) * wa;
            acc.z += bf2f(u0.z) * wa;
            acc.w += bf2f(u0.w) * wa;
        }
        acc.x += bb.x;
        acc.y += bb.y;
        acc.z += bb.z;
        acc.w += bb.w;

        ushort4 o;
        o.x = f2bf(acc.x); o.y = f2bf(acc.y); o.z = f2bf(acc.z); o.w = f2bf(acc.w);
        *(ushort4*)&aggb[(size_t)n * DD + c] = o;

        s0 += acc.x; q0 += acc.x * acc.x;
        s1 += acc.y; q1 += acc.y * acc.y;
        s2 += acc.z; q2 += acc.z * acc.z;
        s3 += acc.w; q3 += acc.w * acc.w;
    }

    f32x4 sv = {s0, s1, s2, s3};
    f32x4 qv = {q0, q1, q2, q3};
    *(f32x4*)&sred[wave * DD + c] = sv;
    *(f32x4*)&qred[wave * DD + c] = qv;
    __syncthreads();
    int d = threadIdx.x;
    float s = sred[d] + sred[DD + d] + sred[2 * DD + d] + sred[3 * DD + d];
    float q = qred[d] + qred[DD + d] + qred[2 * DD + d] + qred[3 * DD + d];
    ps[(size_t)blockIdx.x * DD + d] = s;
    ps2[(size_t)blockIdx.x * DD + d] = q;
}

// ---------------- per-block partials -> colsum/colsumsq (no atomics, no memset) ----------------
__global__ __launch_bounds__(256) void k_bnred(const float* __restrict__ ps,
                                               const float* __restrict__ ps2,
                                               float* __restrict__ colsum,
                                               float* __restrict__ colsumsq) {
    __shared__ float ss[256], qq[256];
    int cgrp = threadIdx.x & 3;
    int r = threadIdx.x >> 2;  // 0..63
    int col = blockIdx.x * 4 + cgrp;
    float s = 0.f, q = 0.f;
    for (int row = r; row < AGG_BLOCKS; row += 64) {
        s += ps[(size_t)row * DD + col];
        q += ps2[(size_t)row * DD + col];
    }
    ss[threadIdx.x] = s;
    qq[threadIdx.x] = q;
    __syncthreads();
    if (threadIdx.x < 4) {
        float S = 0.f, Q = 0.f;
        for (int k = threadIdx.x; k < 256; k += 4) { S += ss[k]; Q += qq[k]; }
        colsum[blockIdx.x * 4 + threadIdx.x] = S;
        colsumsq[blockIdx.x * 4 + threadIdx.x] = Q;
    }
}

// ---------------- BN-apply + ReLU + per-graph-slice pooled partials (no atomics) ----------------
__global__ __launch_bounds__(256) void k_pool(const unsigned short* __restrict__ aggb,
                                              const int* __restrict__ batch,
                                              const float* __restrict__ colsum,
                                              const float* __restrict__ colsumsq,
                                              const float* __restrict__ gamma,
                                              const float* __restrict__ beta,
                                              float* __restrict__ pools, int N) {
    int g = blockIdx.x / POOL_PARTS;
    int p = blockIdx.x % POOL_PARTS;
    int d = threadIdx.x;
    int lo = 0, hi = N;
    while (lo < hi) { int mid = (lo + hi) >> 1; if (batch[mid] < g) lo = mid + 1; else hi = mid; }
    int start = lo;
    lo = 0; hi = N;
    while (lo < hi) { int mid = (lo + hi) >> 1; if (batch[mid] < g + 1) lo = mid + 1; else hi = mid; }
    int len = lo - start;
    int s0 = start + (len * p) / POOL_PARTS;
    int s1 = start + (len * (p + 1)) / POOL_PARTS;

    float m = colsum[d] / (float)N;
    float var = colsumsq[d] / (float)N - m * m;
    float rs = rsqrtf(var + BN_EPS);
    float gm = gamma[d], bt = beta[d];
    float acc = 0.f;
    for (int n = s0; n < s1; ++n) {
        float a = bf2f(aggb[(size_t)n * DD + d]);
        acc += fmaxf(gm * (a - m) * rs + bt, 0.f);
    }
    pools[(size_t)blockIdx.x * DD + d] = acc;
}

// ---------------- head: count + partial-reduce + mean + FC + log_softmax ----------------
__global__ void k_head(const float* __restrict__ pools, const int* __restrict__ batch, int N,
                       const float* __restrict__ Wf, const float* __restrict__ bfv,
                       float* __restrict__ out) {
    int g = blockIdx.x;
    int lane = threadIdx.x;
    __shared__ float pm[DD];
    int lo = 0, hi = N;
    while (lo < hi) { int mid = (lo + hi) >> 1; if (batch[mid] < g) lo = mid + 1; else hi = mid; }
    int start = lo;
    lo = 0; hi = N;
    while (lo < hi) { int mid = (lo + hi) >> 1; if (batch[mid] < g + 1) lo = mid + 1; else hi = mid; }
    float cinv = 1.0f / fmaxf((float)(lo - start), 1.0f);

    for (int k = lane; k < DD; k += 64) {
        float s = 0.f;
#pragma unroll
        for (int p = 0; p < POOL_PARTS; ++p)
            s += pools[((size_t)g * POOL_PARTS + p) * DD + k];
        pm[k] = s * cinv;
    }
    __syncthreads();
    float logit = -INFINITY;
    if (lane < NCLS) {
        float s = bfv[lane];
        for (int k = 0; k < DD; ++k) s += pm[k] * Wf[lane * DD + k];
        logit = s;
    }
    float mx = logit;
#pragma unroll
    for (int off = 32; off; off >>= 1) mx = fmaxf(mx, __shfl_xor(mx, off));
    float ex = (lane < NCLS) ? expf(logit - mx) : 0.f;
    float sum = ex;
#pragma unroll
    for (int off = 32; off; off >>= 1) sum += __shfl_xor(sum, off);
    if (lane < NCLS) out[g * NCLS + lane] = logit - mx - logf(sum);
}

extern "C" void kernel_launch(void* const* d_in, const int* in_sizes, int n_in,
                              void* d_out, int out_size, void* d_ws, size_t ws_size,
                              hipStream_t stream) {
    const float* x     = (const float*)d_in[0];
    const int*   ei    = (const int*)d_in[1];
    const int*   batch = (const int*)d_in[2];
    const float* W     = (const float*)d_in[3];
    const float* b     = (const float*)d_in[4];
    const float* gamma = (const float*)d_in[5];
    const float* beta  = (const float*)d_in[6];
    const float* Wf    = (const float*)d_in[7];
    const float* bf    = (const float*)d_in[8];
    float* out = (float*)d_out;

    const int E = in_sizes[1] / 2;
    const int N = in_sizes[2];
    const int* src = ei;
    const int* dst = ei + E;

    size_t off = 0;
    auto alloc = [&](size_t bytes) {
        void* p = (char*)d_ws + off;
        off += (bytes + 255) & ~(size_t)255;
        return p;
    };
    int*   degcnt    = (int*)alloc((size_t)N * 4);   // zeroed (only memset)
    size_t zbytes = off;
    int*   rowptr    = (int*)alloc(((size_t)N + 1) * 4);
    int*   fillcur   = (int*)alloc((size_t)N * 4);
    unsigned* esw    = (unsigned*)alloc((size_t)E * 4);
    unsigned short* wtg  = (unsigned short*)alloc((size_t)DD * DD * 2);
    unsigned short* xwb  = (unsigned short*)alloc((size_t)N * DD * 2);
    unsigned short* aggb = (unsigned short*)alloc((size_t)N * DD * 2);
    float* ps        = (float*)alloc((size_t)AGG_BLOCKS * DD * 4);
    float* ps2       = (float*)alloc((size_t)AGG_BLOCKS * DD * 4);
    float* pools     = (float*)alloc((size_t)NGRAPH * POOL_PARTS * DD * 4);
    float* colsum    = (float*)alloc(DD * 4);
    float* colsumsq  = (float*)alloc(DD * 4);

    hipMemsetAsync(degcnt, 0, zbytes, stream);

    k_degcount<<<(E + 255) / 256, 256, 0, stream>>>(dst, E, degcnt);
    k_scanwt<<<65, 1024, 0, stream>>>(degcnt, N, E, rowptr, fillcur, W, wtg);
    k_fill<<<(E + 255) / 256, 256, 0, stream>>>(src, dst, degcnt, fillcur, E, esw);

    k_gemm_mfma<<<(N + GBM - 1) / GBM, 512, 0, stream>>>(x, wtg, xwb, N);

    k_aggpull<<<AGG_BLOCKS, 256, 0, stream>>>(xwb, rowptr, esw, degcnt, b, aggb, ps, ps2, N);

    k_bnred<<<DD / 4, 256, 0, stream>>>(ps, ps2, colsum, colsumsq);
    k_pool<<<NGRAPH * POOL_PARTS, 256, 0, stream>>>(aggb, batch, colsum, colsumsq, gamma, beta,
                                                    pools, N);
    k_head<<<NGRAPH, 64, 0, stream>>>(pools, batch, N, Wf, bf, out);
}

// Round 10
// 229.552 us; speedup vs baseline: 1.4407x; 1.4407x over previous
//
#include <hip/hip_runtime.h>

#define DD 256
#define NGRAPH 64
#define NCLS 60
#define BN_EPS 1e-5f
#define SCAN_B 256
#define AGG_BLOCKS 2048
#define AGG_WAVES (AGG_BLOCKS * 4)
#define POOL_PARTS 16

typedef __attribute__((ext_vector_type(8))) short bf16x8;
typedef __attribute__((ext_vector_type(4))) float f32x4;

__device__ __forceinline__ unsigned short f2bf(float f) {
    union { float f; unsigned u; } v;
    v.f = f;
    unsigned r = v.u + 0x7FFFu + ((v.u >> 16) & 1u);  // RNE
    return (unsigned short)(r >> 16);
}
__device__ __forceinline__ float bf2f(unsigned short u) {
    union { unsigned u; float f; } v;
    v.u = ((unsigned)u) << 16;
    return v.f;
}

// ---------------- degree ----------------
__global__ void k_degcount(const int* __restrict__ dst, int E, int* __restrict__ degcnt) {
    int e = blockIdx.x * blockDim.x + threadIdx.x;
    if (e < E) atomicAdd(&degcnt[dst[e]], 1);
}

// ---------------- scan phase 1 (blocks 0..nblk-1) + W transpose (blocks nblk..nblk+255) ----------------
__global__ __launch_bounds__(256) void k_scan1wt(const int* __restrict__ in, int n, int nblk,
                                                 int* __restrict__ out, int* __restrict__ bsum,
                                                 const float* __restrict__ W,
                                                 unsigned short* __restrict__ Wt) {
    if (blockIdx.x >= nblk) {
        int col = blockIdx.x - nblk;          // 0..255: column of W -> row of Wt
        int k = threadIdx.x;
        Wt[col * DD + k] = f2bf(W[k * DD + col]);
        return;
    }
    __shared__ int sm[SCAN_B];
    int i = blockIdx.x * SCAN_B + threadIdx.x;
    int v = (i < n) ? in[i] : 0;
    sm[threadIdx.x] = v;
    __syncthreads();
    int acc = v;
    for (int off = 1; off < SCAN_B; off <<= 1) {
        int t = (threadIdx.x >= off) ? sm[threadIdx.x - off] : 0;
        __syncthreads();
        acc += t;
        sm[threadIdx.x] = acc;
        __syncthreads();
    }
    if (i < n) out[i] = acc - v;
    if (threadIdx.x == SCAN_B - 1) bsum[blockIdx.x] = acc;
}

__global__ void k_scan2(int* __restrict__ bsum, int nb, int* __restrict__ total) {
    __shared__ int sm[SCAN_B];
    __shared__ int carry;
    if (threadIdx.x == 0) carry = 0;
    __syncthreads();
    for (int base = 0; base < nb; base += SCAN_B) {
        int i = base + threadIdx.x;
        int v = (i < nb) ? bsum[i] : 0;
        sm[threadIdx.x] = v;
        __syncthreads();
        int acc = v;
        for (int off = 1; off < SCAN_B; off <<= 1) {
            int t = (threadIdx.x >= off) ? sm[threadIdx.x - off] : 0;
            __syncthreads();
            acc += t;
            sm[threadIdx.x] = acc;
            __syncthreads();
        }
        if (i < nb) bsum[i] = carry + acc - v;
        __syncthreads();
        if (threadIdx.x == SCAN_B - 1) carry += acc;
        __syncthreads();
    }
    if (threadIdx.x == 0 && total) *total = carry;
}

// scan phase 3: finalize rowptr and initialize fill cursors
__global__ void k_scan3f(int* __restrict__ rowptr, int n, const int* __restrict__ bsum,
                         int* __restrict__ fillcur) {
    int i = blockIdx.x * SCAN_B + threadIdx.x;
    if (i < n) {
        int v = rowptr[i] + bsum[blockIdx.x];
        rowptr[i] = v;
        fillcur[i] = v;
    }
}

// ---------------- CSR bucket fill: packed 4B (src:16 | norm_bf16:16) ----------------
__global__ void k_fill(const int* __restrict__ src, const int* __restrict__ dst,
                       const int* __restrict__ degcnt, int* __restrict__ fillcur,
                       int E, unsigned* __restrict__ esw) {
    int e = blockIdx.x * blockDim.x + threadIdx.x;
    if (e >= E) return;
    int s = src[e], d = dst[e];
    float w = rsqrtf((float)(degcnt[s] + 1)) * rsqrtf((float)(degcnt[d] + 1));
    int slot = atomicAdd(&fillcur[d], 1);
    esw[slot] = (unsigned)s | ((unsigned)f2bf(w) << 16);  // N < 65536
}

// ---------------- MFMA GEMM: 128x256 tile (full width), 512 threads ----------------
#define GBM 128
#define GBN 256
__global__ __launch_bounds__(512) void k_gemm_mfma(const float* __restrict__ A,
                                                   const unsigned short* __restrict__ Wtg,
                                                   unsigned short* __restrict__ C, int M) {
    __shared__ short Wt[GBN * 256];  // full weight [n][k] bf16, XOR-swizzled, 128 KB
    __shared__ short At[GBM * 32];   // [row][k] bf16 per k-step, swizzled, 8 KB
    const int tid = threadIdx.x;
    const int wave = tid >> 6;
    const int lane = tid & 63;
    const int row0 = blockIdx.x * GBM;

#pragma unroll
    for (int i = 0; i < 16; ++i) {
        int cid = tid + i * 512;
        int n = cid >> 5;
        int k0 = (cid & 31) * 8;
        bf16x8 pk = *(const bf16x8*)&Wtg[(size_t)n * DD + k0];
        int byte = (n * 512 + k0 * 2) ^ ((n & 7) << 4);
        *(bf16x8*)((char*)Wt + byte) = pk;
    }

    f32x4 acc[16];
#pragma unroll
    for (int j = 0; j < 16; ++j) acc[j] = (f32x4){0.f, 0.f, 0.f, 0.f};

    const int arow = tid >> 2;
    const int aslot = tid & 3;
    const int grow = row0 + arow;
    const int frow = wave * 16 + (lane & 15);
    const int g = lane >> 4;
    const int abyte_st = (arow * 64 + aslot * 16) ^ ((arow & 3) << 4);
    const float* ap = (grow < M) ? &A[(size_t)grow * DD + aslot * 8] : nullptr;

    float4 va = make_float4(0.f, 0.f, 0.f, 0.f);
    float4 vb = make_float4(0.f, 0.f, 0.f, 0.f);
    if (ap) { va = *(const float4*)ap; vb = *(const float4*)(ap + 4); }

    for (int kb = 0; kb < DD; kb += 32) {
        __syncthreads();
        {
            bf16x8 pk;
            pk[0] = (short)f2bf(va.x); pk[1] = (short)f2bf(va.y);
            pk[2] = (short)f2bf(va.z); pk[3] = (short)f2bf(va.w);
            pk[4] = (short)f2bf(vb.x); pk[5] = (short)f2bf(vb.y);
            pk[6] = (short)f2bf(vb.z); pk[7] = (short)f2bf(vb.w);
            *(bf16x8*)((char*)At + abyte_st) = pk;
        }
        __syncthreads();

        if (kb + 32 < DD && ap) {
            va = *(const float4*)(ap + kb + 32);
            vb = *(const float4*)(ap + kb + 36);
        }

        int abyte = (frow * 64 + g * 16) ^ ((frow & 3) << 4);
        bf16x8 af = *(const bf16x8*)((const char*)At + abyte);
#pragma unroll
        for (int j = 0; j < 16; ++j) {
            int n = j * 16 + (lane & 15);
            int bbyte = (n * 512 + (kb + g * 8) * 2) ^ ((n & 7) << 4);
            bf16x8 bfr = *(const bf16x8*)((const char*)Wt + bbyte);
            acc[j] = __builtin_amdgcn_mfma_f32_16x16x32_bf16(af, bfr, acc[j], 0, 0, 0);
        }
    }

#pragma unroll
    for (int j = 0; j < 16; ++j) {
        int col = j * 16 + (lane & 15);
#pragma unroll
        for (int r = 0; r < 4; ++r) {
            int row = row0 + wave * 16 + g * 4 + r;
            if (row < M) C[(size_t)row * DD + col] = f2bf(acc[j][r]);
        }
    }
}

// ---------------- pull aggregation (persistent, full row/wave) + BN partials ----------------
__global__ __launch_bounds__(256) void k_aggpull(const unsigned short* __restrict__ xwb,
                                                 const int* __restrict__ rowptr,
                                                 const unsigned* __restrict__ esw,
                                                 const int* __restrict__ degcnt,
                                                 const float* __restrict__ b,
                                                 unsigned short* __restrict__ aggb,
                                                 float* __restrict__ ps,
                                                 float* __restrict__ ps2, int N) {
    __shared__ float sred[4 * DD];
    __shared__ float qred[4 * DD];
    const int lane = threadIdx.x & 63;
    const int wave = threadIdx.x >> 6;
    const int c = lane * 4;
    const int gw = (blockIdx.x * blockDim.x + threadIdx.x) >> 6;
    const float4 bb = *(const float4*)&b[c];

    float s0 = 0.f, s1 = 0.f, s2 = 0.f, s3 = 0.f;
    float q0 = 0.f, q1 = 0.f, q2 = 0.f, q3 = 0.f;

    for (int n = gw; n < N; n += AGG_WAVES) {
        float di = rsqrtf((float)(degcnt[n] + 1));
        float w0 = di * di;
        ushort4 v = *(const ushort4*)&xwb[(size_t)n * DD + c];
        float4 acc = make_float4(bf2f(v.x) * w0, bf2f(v.y) * w0, bf2f(v.z) * w0, bf2f(v.w) * w0);

        int j0 = rowptr[n], j1 = rowptr[n + 1];
        int j = j0;
        for (; j + 3 < j1; j += 4) {
            unsigned e0 = esw[j + 0], e1 = esw[j + 1], e2 = esw[j + 2], e3 = esw[j + 3];
            ushort4 u0 = *(const ushort4*)&xwb[(size_t)(e0 & 0xFFFFu) * DD + c];
            ushort4 u1 = *(const ushort4*)&xwb[(size_t)(e1 & 0xFFFFu) * DD + c];
            ushort4 u2 = *(const ushort4*)&xwb[(size_t)(e2 & 0xFFFFu) * DD + c];
            ushort4 u3 = *(const ushort4*)&xwb[(size_t)(e3 & 0xFFFFu) * DD + c];
            float wa = bf2f((unsigned short)(e0 >> 16));
            float wb = bf2f((unsigned short)(e1 >> 16));
            float wc = bf2f((unsigned short)(e2 >> 16));
            float wd = bf2f((unsigned short)(e3 >> 16));
            acc.x += bf2f(u0.x) * wa + bf2f(u1.x) * wb + bf2f(u2.x) * wc + bf2f(u3.x) * wd;
            acc.y += bf2f(u0.y) * wa + bf2f(u1.y) * wb + bf2f(u2.y) * wc + bf2f(u3.y) * wd;
            acc.z += bf2f(u0.z) * wa + bf2f(u1.z) * wb + bf2f(u2.z) * wc + bf2f(u3.z) * wd;
            acc.w += bf2f(u0.w) * wa + bf2f(u1.w) * wb + bf2f(u2.w) * wc + bf2f(u3.w) * wd;
        }
        for (; j < j1; ++j) {
            unsigned e0 = esw[j];
            float wa = bf2f((unsigned short)(e0 >> 16));
            ushort4 u0 = *(const ushort4*)&xwb[(size_t)(e0 & 0xFFFFu) * DD + c];
            acc.x += bf2f(u0.x) * wa;
            acc.y += bf2f(u0.y) * wa;
            acc.z += bf2f(u0.z) * wa;
            acc.w += bf2f(u0.w) * wa;
        }
        acc.x += bb.x;
        acc.y += bb.y;
        acc.z += bb.z;
        acc.w += bb.w;

        ushort4 o;
        o.x = f2bf(acc.x); o.y = f2bf(acc.y); o.z = f2bf(acc.z); o.w = f2bf(acc.w);
        *(ushort4*)&aggb[(size_t)n * DD + c] = o;

        s0 += acc.x; q0 += acc.x * acc.x;
        s1 += acc.y; q1 += acc.y * acc.y;
        s2 += acc.z; q2 += acc.z * acc.z;
        s3 += acc.w; q3 += acc.w * acc.w;
    }

    f32x4 sv = {s0, s1, s2, s3};
    f32x4 qv = {q0, q1, q2, q3};
    *(f32x4*)&sred[wave * DD + c] = sv;
    *(f32x4*)&qred[wave * DD + c] = qv;
    __syncthreads();
    int d = threadIdx.x;
    float s = sred[d] + sred[DD + d] + sred[2 * DD + d] + sred[3 * DD + d];
    float q = qred[d] + qred[DD + d] + qred[2 * DD + d] + qred[3 * DD + d];
    ps[(size_t)blockIdx.x * DD + d] = s;
    ps2[(size_t)blockIdx.x * DD + d] = q;
}

// ---------------- per-block partials -> colsum/colsumsq (no atomics) ----------------
__global__ __launch_bounds__(256) void k_bnred(const float* __restrict__ ps,
                                               const float* __restrict__ ps2,
                                               float* __restrict__ colsum,
                                               float* __restrict__ colsumsq) {
    __shared__ float ss[256], qq[256];
    int cgrp = threadIdx.x & 3;
    int r = threadIdx.x >> 2;  // 0..63
    int col = blockIdx.x * 4 + cgrp;
    float s = 0.f, q = 0.f;
    for (int row = r; row < AGG_BLOCKS; row += 64) {
        s += ps[(size_t)row * DD + col];
        q += ps2[(size_t)row * DD + col];
    }
    ss[threadIdx.x] = s;
    qq[threadIdx.x] = q;
    __syncthreads();
    if (threadIdx.x < 4) {
        float S = 0.f, Q = 0.f;
        for (int k = threadIdx.x; k < 256; k += 4) { S += ss[k]; Q += qq[k]; }
        colsum[blockIdx.x * 4 + threadIdx.x] = S;
        colsumsq[blockIdx.x * 4 + threadIdx.x] = Q;
    }
}

// ---------------- BN-apply + ReLU + per-graph-slice pooled partials (no atomics) ----------------
__global__ __launch_bounds__(256) void k_pool(const unsigned short* __restrict__ aggb,
                                              const int* __restrict__ batch,
                                              const float* __restrict__ colsum,
                                              const float* __restrict__ colsumsq,
                                              const float* __restrict__ gamma,
                                              const float* __restrict__ beta,
                                              float* __restrict__ pools, int N) {
    int g = blockIdx.x / POOL_PARTS;
    int p = blockIdx.x % POOL_PARTS;
    int d = threadIdx.x;
    int lo = 0, hi = N;
    while (lo < hi) { int mid = (lo + hi) >> 1; if (batch[mid] < g) lo = mid + 1; else hi = mid; }
    int start = lo;
    lo = 0; hi = N;
    while (lo < hi) { int mid = (lo + hi) >> 1; if (batch[mid] < g + 1) lo = mid + 1; else hi = mid; }
    int len = lo - start;
    int s0 = start + (len * p) / POOL_PARTS;
    int s1 = start + (len * (p + 1)) / POOL_PARTS;

    float m = colsum[d] / (float)N;
    float var = colsumsq[d] / (float)N - m * m;
    float rs = rsqrtf(var + BN_EPS);
    float gm = gamma[d], bt = beta[d];
    float acc = 0.f;
    for (int n = s0; n < s1; ++n) {
        float a = bf2f(aggb[(size_t)n * DD + d]);
        acc += fmaxf(gm * (a - m) * rs + bt, 0.f);
    }
    pools[(size_t)blockIdx.x * DD + d] = acc;
}

// ---------------- head: count + partial-reduce + mean + FC + log_softmax ----------------
__global__ void k_head(const float* __restrict__ pools, const int* __restrict__ batch, int N,
                       const float* __restrict__ Wf, const float* __restrict__ bfv,
                       float* __restrict__ out) {
    int g = blockIdx.x;
    int lane = threadIdx.x;
    __shared__ float pm[DD];
    int lo = 0, hi = N;
    while (lo < hi) { int mid = (lo + hi) >> 1; if (batch[mid] < g) lo = mid + 1; else hi = mid; }
    int start = lo;
    lo = 0; hi = N;
    while (lo < hi) { int mid = (lo + hi) >> 1; if (batch[mid] < g + 1) lo = mid + 1; else hi = mid; }
    float cinv = 1.0f / fmaxf((float)(lo - start), 1.0f);

    for (int k = lane; k < DD; k += 64) {
        float s = 0.f;
#pragma unroll
        for (int p = 0; p < POOL_PARTS; ++p)
            s += pools[((size_t)g * POOL_PARTS + p) * DD + k];
        pm[k] = s * cinv;
    }
    __syncthreads();
    float logit = -INFINITY;
    if (lane < NCLS) {
        float s = bfv[lane];
        for (int k = 0; k < DD; ++k) s += pm[k] * Wf[lane * DD + k];
        logit = s;
    }
    float mx = logit;
#pragma unroll
    for (int off = 32; off; off >>= 1) mx = fmaxf(mx, __shfl_xor(mx, off));
    float ex = (lane < NCLS) ? expf(logit - mx) : 0.f;
    float sum = ex;
#pragma unroll
    for (int off = 32; off; off >>= 1) sum += __shfl_xor(sum, off);
    if (lane < NCLS) out[g * NCLS + lane] = logit - mx - logf(sum);
}

extern "C" void kernel_launch(void* const* d_in, const int* in_sizes, int n_in,
                              void* d_out, int out_size, void* d_ws, size_t ws_size,
                              hipStream_t stream) {
    const float* x     = (const float*)d_in[0];
    const int*   ei    = (const int*)d_in[1];
    const int*   batch = (const int*)d_in[2];
    const float* W     = (const float*)d_in[3];
    const float* b     = (const float*)d_in[4];
    const float* gamma = (const float*)d_in[5];
    const float* beta  = (const float*)d_in[6];
    const float* Wf    = (const float*)d_in[7];
    const float* bf    = (const float*)d_in[8];
    float* out = (float*)d_out;

    const int E = in_sizes[1] / 2;
    const int N = in_sizes[2];
    const int* src = ei;
    const int* dst = ei + E;

    size_t off = 0;
    auto alloc = [&](size_t bytes) {
        void* p = (char*)d_ws + off;
        off += (bytes + 255) & ~(size_t)255;
        return p;
    };
    int*   degcnt    = (int*)alloc((size_t)N * 4);   // zeroed (only memset)
    size_t zbytes = off;
    int*   rowptr    = (int*)alloc(((size_t)N + 1) * 4);
    int*   fillcur   = (int*)alloc((size_t)N * 4);
    unsigned* esw    = (unsigned*)alloc((size_t)E * 4);
    unsigned short* wtg  = (unsigned short*)alloc((size_t)DD * DD * 2);
    unsigned short* xwb  = (unsigned short*)alloc((size_t)N * DD * 2);
    unsigned short* aggb = (unsigned short*)alloc((size_t)N * DD * 2);
    float* ps        = (float*)alloc((size_t)AGG_BLOCKS * DD * 4);
    float* ps2       = (float*)alloc((size_t)AGG_BLOCKS * DD * 4);
    float* pools     = (float*)alloc((size_t)NGRAPH * POOL_PARTS * DD * 4);
    float* colsum    = (float*)alloc(DD * 4);
    float* colsumsq  = (float*)alloc(DD * 4);
    int*   bsum      = (int*)alloc(((size_t)N / SCAN_B + 2) * 4);

    hipMemsetAsync(degcnt, 0, zbytes, stream);

    k_degcount<<<(E + 255) / 256, 256, 0, stream>>>(dst, E, degcnt);

    int nblk = (N + SCAN_B - 1) / SCAN_B;
    k_scan1wt<<<nblk + DD, SCAN_B, 0, stream>>>(degcnt, N, nblk, rowptr, bsum, W, wtg);
    k_scan2<<<1, SCAN_B, 0, stream>>>(bsum, nblk, &rowptr[N]);
    k_scan3f<<<nblk, SCAN_B, 0, stream>>>(rowptr, N, bsum, fillcur);
    k_fill<<<(E + 255) / 256, 256, 0, stream>>>(src, dst, degcnt, fillcur, E, esw);

    k_gemm_mfma<<<(N + GBM - 1) / GBM, 512, 0, stream>>>(x, wtg, xwb, N);

    k_aggpull<<<AGG_BLOCKS, 256, 0, stream>>>(xwb, rowptr, esw, degcnt, b, aggb, ps, ps2, N);

    k_bnred<<<DD / 4, 256, 0, stream>>>(ps, ps2, colsum, colsumsq);
    k_pool<<<NGRAPH * POOL_PARTS, 256, 0, stream>>>(aggb, batch, colsum, colsumsq, gamma, beta,
                                                    pools, N);
    k_head<<<NGRAPH, 64, 0, stream>>>(pools, batch, N, Wf, bf, out);
}